// Round 1
// baseline (431.617 us; speedup 1.0000x reference)
//
#include <hip/hip_runtime.h>
#include <hip/hip_fp16.h>

typedef _Float16 f16;
typedef _Float16 f16x4 __attribute__((ext_vector_type(4)));
typedef _Float16 f16x8 __attribute__((ext_vector_type(8)));
typedef float f32x4 __attribute__((ext_vector_type(4)));

static constexpr int CB = 8;      // batch
static constexpr int CC = 256;    // channels = Co
static constexpr int CN = 4096;   // tokens = H*W
static constexpr float LOG2E = 1.44269504088896f;

#define MFMA(a, b, c) __builtin_amdgcn_mfma_f32_16x16x32_f16((a), (b), (c), 0, 0, 0)

__global__ __launch_bounds__(256) void prep_weights(const float* __restrict__ wq,
    const float* __restrict__ wk, const float* __restrict__ wv,
    const float* __restrict__ wo, f16* __restrict__ W) {
  int i = blockIdx.x * 256 + threadIdx.x;   // 65536 threads, one elem of each matrix
  W[i]          = (f16)wq[i];
  W[65536 + i]  = (f16)wk[i];
  W[131072 + i] = (f16)wv[i];
  W[196608 + i] = (f16)wo[i];
}

// x [B,C,N] fp32  ->  Q,K [B,N,256] f16 ; V^T [B,256,N] f16
__global__ __launch_bounds__(256) void qkv_kernel(const float* __restrict__ x,
    const f16* __restrict__ Wq, const f16* __restrict__ Wk, const f16* __restrict__ Wv,
    const float* __restrict__ bq, const float* __restrict__ bk, const float* __restrict__ bv,
    f16* __restrict__ Q, f16* __restrict__ K, f16* __restrict__ Vt) {
  __shared__ f16 xf[64][264];               // [n][c], +8 pad -> 2-way banks only
  const int b  = blockIdx.x >> 6;
  const int n0 = (blockIdx.x & 63) << 6;
  const int t  = threadIdx.x;
  const float* xb = x + (size_t)b * CC * CN;
  {
    int c = t >> 4;
    const int nn = (t & 15) << 2;
    #pragma unroll
    for (int pass = 0; pass < 16; ++pass, c += 16) {
      const float4 v = *(const float4*)(xb + (size_t)c * CN + n0 + nn);
      xf[nn + 0][c] = (f16)v.x;
      xf[nn + 1][c] = (f16)v.y;
      xf[nn + 2][c] = (f16)v.z;
      xf[nn + 3][c] = (f16)v.w;
    }
  }
  __syncthreads();
  const int w = t >> 6, l = t & 63, lr = l & 15, lh = l >> 4;

  f16x8 xff[8];
  #pragma unroll
  for (int kk = 0; kk < 8; ++kk)
    xff[kk] = *(const f16x8*)&xf[w * 16 + lr][kk * 32 + lh * 8];

  const size_t qkrow = ((size_t)b * CN + n0 + w * 16 + lr) * CC;

  // Q and K in transposed orientation D[o][n]: lane holds 4 consecutive o at fixed n
  #pragma unroll 1
  for (int mat = 0; mat < 2; ++mat) {
    const f16* W = mat ? Wk : Wq;
    const float* bias = mat ? bk : bq;
    f16* dst = mat ? K : Q;
    f32x4 acc[16];
    #pragma unroll
    for (int m = 0; m < 16; ++m) acc[m] = f32x4{0.f, 0.f, 0.f, 0.f};
    #pragma unroll
    for (int kk = 0; kk < 8; ++kk) {
      #pragma unroll
      for (int m = 0; m < 16; ++m) {
        f16x8 af = *(const f16x8*)&W[(size_t)(m * 16 + lr) * CC + kk * 32 + lh * 8];
        acc[m] = MFMA(af, xff[kk], acc[m]);
      }
    }
    #pragma unroll
    for (int m = 0; m < 16; ++m) {
      const int o = m * 16 + lh * 4;
      const float4 bs = *(const float4*)&bias[o];
      f16x4 hv;
      hv[0] = (f16)(acc[m][0] + bs.x);
      hv[1] = (f16)(acc[m][1] + bs.y);
      hv[2] = (f16)(acc[m][2] + bs.z);
      hv[3] = (f16)(acc[m][3] + bs.w);
      *(f16x4*)&dst[qkrow + o] = hv;
    }
  }
  // V in normal orientation D[n][o]: lane holds 4 consecutive n at fixed o -> V^T store
  {
    f32x4 acc[16];
    #pragma unroll
    for (int m = 0; m < 16; ++m) acc[m] = f32x4{0.f, 0.f, 0.f, 0.f};
    #pragma unroll
    for (int kk = 0; kk < 8; ++kk) {
      #pragma unroll
      for (int m = 0; m < 16; ++m) {
        f16x8 bf = *(const f16x8*)&Wv[(size_t)(m * 16 + lr) * CC + kk * 32 + lh * 8];
        acc[m] = MFMA(xff[kk], bf, acc[m]);
      }
    }
    #pragma unroll
    for (int m = 0; m < 16; ++m) {
      const int o = m * 16 + lr;
      const float bvs = bv[o];
      f16x4 hv;
      #pragma unroll
      for (int j = 0; j < 4; ++j) hv[j] = (f16)(acc[m][j] + bvs);
      *(f16x4*)&Vt[((size_t)b * CC + o) * CN + n0 + w * 16 + lh * 4] = hv;
    }
  }
}

// flash attention: Q,K [B,N,256], V^T [B,256,N] -> O [B,N,256], no scaling, softmax over kv
__global__ __launch_bounds__(256) void attn_kernel(const f16* __restrict__ Q,
    const f16* __restrict__ K, const f16* __restrict__ Vt, f16* __restrict__ O) {
  __shared__ f16 Kl[32][264];      // kv-tile [kv][c], 2-way banks
  __shared__ f16 Vl[256][40];      // V^T tile [o][kv], 2-way banks
  __shared__ f16 Pl[4][16][40];    // per-wave P relayout [q][kv]
  // bijective XCD swizzle: each XCD gets one batch -> K+V (4MB f16) fits its L2
  const int lb = ((blockIdx.x & 7) << 6) | (blockIdx.x >> 3);
  const int b  = lb >> 6;
  const int q0 = (lb & 63) << 6;
  const int t  = threadIdx.x;
  const int w = t >> 6, l = t & 63, lr = l & 15, lh = l >> 4;
  const f16* Qb = Q  + (size_t)b * CN * CC;
  const f16* Kb = K  + (size_t)b * CN * CC;
  const f16* Vb = Vt + (size_t)b * CC * CN;

  f16x8 qf[8];
  {
    const f16* qrow = Qb + (size_t)(q0 + w * 16 + lr) * CC;
    #pragma unroll
    for (int kk = 0; kk < 8; ++kk) qf[kk] = *(const f16x8*)&qrow[kk * 32 + lh * 8];
  }
  f32x4 oacc[16];
  #pragma unroll
  for (int m = 0; m < 16; ++m) oacc[m] = f32x4{0.f, 0.f, 0.f, 0.f};
  float mrun = -1e30f, lrun = 0.0f;

  const int kr = t >> 3, kc = t & 7;   // K staging: 8 thr/row x 32 rows
  const int vo = t >> 2, vc = t & 3;   // V staging: 4 thr/row x 64 rows x 4 passes

  for (int kv0 = 0; kv0 < CN; kv0 += 32) {
    __syncthreads();
    {
      const f16* src = Kb + (size_t)(kv0 + kr) * CC;
      #pragma unroll
      for (int i = 0; i < 4; ++i) {
        const int e = (kc + i * 8) * 8;
        *(f16x8*)&Kl[kr][e] = *(const f16x8*)&src[e];
      }
      #pragma unroll
      for (int i = 0; i < 4; ++i) {
        const int o = vo + i * 64;
        *(f16x8*)&Vl[o][vc * 8] = *(const f16x8*)&Vb[(size_t)o * CN + kv0 + vc * 8];
      }
    }
    __syncthreads();

    // swapped QK^T: S^T[kv][q] = mfma(A=K, B=Q); lane: q-row=lr, kv rows m*16+lh*4+j
    f32x4 sacc[2];
    sacc[0] = f32x4{0.f, 0.f, 0.f, 0.f};
    sacc[1] = f32x4{0.f, 0.f, 0.f, 0.f};
    #pragma unroll
    for (int kk = 0; kk < 8; ++kk) {
      #pragma unroll
      for (int m = 0; m < 2; ++m) {
        f16x8 kf = *(const f16x8*)&Kl[m * 16 + lr][kk * 32 + lh * 8];
        sacc[m] = MFMA(kf, qf[kk], sacc[m]);
      }
    }
    // online softmax: 8 in-lane values + 2 shuffles = full 32-wide row reduce
    float pmax = -1e30f;
    #pragma unroll
    for (int m = 0; m < 2; ++m)
      #pragma unroll
      for (int j = 0; j < 4; ++j) pmax = fmaxf(pmax, sacc[m][j]);
    pmax = fmaxf(pmax, __shfl_xor(pmax, 16));
    pmax = fmaxf(pmax, __shfl_xor(pmax, 32));
    const float mnew  = fmaxf(mrun, pmax);
    const float alpha = exp2f((mrun - mnew) * LOG2E);
    float psum = 0.0f;
    f16x4 plo, phi;
    #pragma unroll
    for (int j = 0; j < 4; ++j) {
      const float p0 = exp2f((sacc[0][j] - mnew) * LOG2E);
      const float p1 = exp2f((sacc[1][j] - mnew) * LOG2E);
      psum += p0 + p1;
      plo[j] = (f16)p0;
      phi[j] = (f16)p1;
    }
    psum += __shfl_xor(psum, 16);
    psum += __shfl_xor(psum, 32);
    lrun = lrun * alpha + psum;
    mrun = mnew;
    // wave-private LDS round-trip: S^T frag layout -> x32 A-frag layout
    *(f16x4*)&Pl[w][lr][lh * 4]      = plo;
    *(f16x4*)&Pl[w][lr][16 + lh * 4] = phi;
    // rescale O by alpha of the row each acc element belongs to
    float fr[4];
    #pragma unroll
    for (int j = 0; j < 4; ++j) fr[j] = __shfl(alpha, lh * 4 + j);
    #pragma unroll
    for (int m = 0; m < 16; ++m) {
      oacc[m][0] *= fr[0]; oacc[m][1] *= fr[1];
      oacc[m][2] *= fr[2]; oacc[m][3] *= fr[3];
    }
    const f16x8 pf = *(const f16x8*)&Pl[w][lr][lh * 8];
    #pragma unroll
    for (int m = 0; m < 16; ++m) {
      f16x8 vf = *(const f16x8*)&Vl[m * 16 + lr][lh * 8];
      oacc[m] = MFMA(pf, vf, oacc[m]);
    }
  }
  const float inv = 1.0f / lrun;
  float fr[4];
  #pragma unroll
  for (int j = 0; j < 4; ++j) fr[j] = __shfl(inv, lh * 4 + j);
  f16* orow = O + ((size_t)b * CN + q0 + w * 16 + lh * 4) * CC;
  #pragma unroll
  for (int m = 0; m < 16; ++m) {
    #pragma unroll
    for (int j = 0; j < 4; ++j)
      orow[(size_t)j * CC + m * 16 + lr] = (f16)(oacc[m][j] * fr[j]);
  }
}

// out[b,c,n] = sum_o O[b,n,o] * Wo[c,o] + bo[c]   (fp32 output, [B,C,H,W] layout)
__global__ __launch_bounds__(256) void oproj_kernel(const f16* __restrict__ O,
    const f16* __restrict__ Wo, const float* __restrict__ bo, float* __restrict__ out) {
  const int b  = blockIdx.x >> 6;
  const int n0 = (blockIdx.x & 63) << 6;
  const int t  = threadIdx.x;
  const int w = t >> 6, l = t & 63, lr = l & 15, lh = l >> 4;
  const f16* orow = O + ((size_t)b * CN + n0 + w * 16 + lr) * CC;
  f32x4 acc[16];
  #pragma unroll
  for (int m = 0; m < 16; ++m) acc[m] = f32x4{0.f, 0.f, 0.f, 0.f};
  #pragma unroll
  for (int kk = 0; kk < 8; ++kk) {
    const f16x8 bf = *(const f16x8*)&orow[kk * 32 + lh * 8];
    #pragma unroll
    for (int m = 0; m < 16; ++m) {
      f16x8 af = *(const f16x8*)&Wo[(size_t)(m * 16 + lr) * CC + kk * 32 + lh * 8];
      acc[m] = MFMA(af, bf, acc[m]);
    }
  }
  #pragma unroll
  for (int m = 0; m < 16; ++m) {
    const int c = m * 16 + lh * 4;
    const float4 bv4 = *(const float4*)&bo[c];
    const size_t base = ((size_t)b * CC + c) * CN + n0 + w * 16 + lr;
    out[base + 0 * (size_t)CN] = acc[m][0] + bv4.x;
    out[base + 1 * (size_t)CN] = acc[m][1] + bv4.y;
    out[base + 2 * (size_t)CN] = acc[m][2] + bv4.z;
    out[base + 3 * (size_t)CN] = acc[m][3] + bv4.w;
  }
}

extern "C" void kernel_launch(void* const* d_in, const int* in_sizes, int n_in,
                              void* d_out, int out_size, void* d_ws, size_t ws_size,
                              hipStream_t stream) {
  const float* x  = (const float*)d_in[0];
  const float* wq = (const float*)d_in[1];
  const float* bq = (const float*)d_in[2];
  const float* wk = (const float*)d_in[3];
  const float* bk = (const float*)d_in[4];
  const float* wv = (const float*)d_in[5];
  const float* bv = (const float*)d_in[6];
  const float* wo = (const float*)d_in[7];
  const float* bo = (const float*)d_in[8];

  f16* W  = (f16*)d_ws;                     // 4 x 65536 f16 weights
  f16* Qd = W + 262144;                     // [B,N,256]
  f16* Kd = Qd + (size_t)CB * CN * CC;      // [B,N,256]
  f16* Vt = Kd + (size_t)CB * CN * CC;      // [B,256,N]
  f16* Od = Vt + (size_t)CB * CN * CC;      // [B,N,256]

  prep_weights<<<256, 256, 0, stream>>>(wq, wk, wv, wo, W);
  qkv_kernel<<<512, 256, 0, stream>>>(x, W, W + 65536, W + 131072, bq, bk, bv, Qd, Kd, Vt);
  attn_kernel<<<512, 256, 0, stream>>>(Qd, Kd, Vt, Od);
  oproj_kernel<<<512, 256, 0, stream>>>(Od, W + 196608, bo, (float*)d_out);
}